// Round 2
// baseline (1374.604 us; speedup 1.0000x reference)
//
#include <hip/hip_runtime.h>
#include <math.h>

typedef unsigned short u16;
typedef __attribute__((ext_vector_type(4))) float f32x4;
typedef __attribute__((ext_vector_type(8))) __bf16 bf16x8;
typedef __attribute__((ext_vector_type(8))) u16 u16x8;
typedef __attribute__((ext_vector_type(4))) u16 u16x4;

#define D_MODEL 4096
#define NQKV    12288
#define BL      2048
#define L_SEQ   1024
#define NH      32
#define DH      128

__device__ __forceinline__ u16 f2bf(float f) {
    union { float f; unsigned u; } v; v.f = f;
    unsigned r = (v.u + 0x7fffu + ((v.u >> 16) & 1u)) >> 16;
    return (u16)r;
}
__device__ __forceinline__ float bf2f(u16 b) {
    union { unsigned u; float f; } v; v.u = ((unsigned)b) << 16;
    return v.f;
}
__device__ __forceinline__ void gload_lds16(const void* g, void* l) {
    __builtin_amdgcn_global_load_lds((const __attribute__((address_space(1))) void*)g,
                                     (__attribute__((address_space(3))) void*)l, 16, 0, 0);
}
__device__ __forceinline__ f32x4 mfma_bf16(bf16x8 a, bf16x8 b, f32x4 c) {
    return __builtin_amdgcn_mfma_f32_16x16x32_bf16(a, b, c, 0, 0, 0);
}

// ---------------- fp32 -> bf16 convert (hidden states) ----------------
__global__ __launch_bounds__(256) void convert_f32_bf16(const float* __restrict__ in,
                                                        u16* __restrict__ out, int n4) {
    int i = blockIdx.x * 256 + threadIdx.x;
    if (i < n4) {
        float4 v = ((const float4*)in)[i];
        u16x4 o;
        o[0] = f2bf(v.x); o[1] = f2bf(v.y); o[2] = f2bf(v.z); o[3] = f2bf(v.w);
        ((u16x4*)out)[i] = o;
    }
}

// ---------------- fp32 W[K][N] -> bf16 Wt[N][K] ----------------
__global__ __launch_bounds__(256) void transpose_convert(const float* __restrict__ W,
                                                         u16* __restrict__ Wt, int K, int N) {
    __shared__ float t[32][33];
    int tx = threadIdx.x, ty = threadIdx.y;
    int nt = blockIdx.x * 32, kt = blockIdx.y * 32;
#pragma unroll
    for (int i = 0; i < 4; ++i)
        t[ty + i * 8][tx] = W[(size_t)(kt + ty + i * 8) * N + nt + tx];
    __syncthreads();
#pragma unroll
    for (int i = 0; i < 4; ++i)
        Wt[(size_t)(nt + ty + i * 8) * K + kt + tx] = f2bf(t[tx][ty + i * 8]);
}

// ---------------- vmask + expert row lists (deterministic scan) ----------------
__global__ __launch_bounds__(256) void mask_scan(const int* __restrict__ tt,
                                                 int* __restrict__ lists,
                                                 int* __restrict__ counts) {
    __shared__ int buf[256];
    int tid = threadIdx.x;
    int base = tid * 8;
    int flags = 0, cv = 0;
#pragma unroll
    for (int j = 0; j < 8; ++j) {
        int i = base + j;
        int l = i & (L_SEQ - 1);
        int f = (l < L_SEQ - 1) && (tt[i] == 1) && (tt[i + 1] == 1);
        flags |= f << j; cv += f;
    }
    buf[tid] = cv; __syncthreads();
    for (int d = 1; d < 256; d <<= 1) {
        int t = (tid >= d) ? buf[tid - d] : 0;
        __syncthreads();
        buf[tid] += t;
        __syncthreads();
    }
    int vs = buf[tid] - cv;     // exclusive vis prefix
    int ls = base - vs;         // exclusive lang prefix
    int total_v = buf[255];
#pragma unroll
    for (int j = 0; j < 8; ++j) {
        int i = base + j;
        if ((flags >> j) & 1) lists[vs++] = i;
        else                  lists[2048 + ls++] = i;
    }
    if (tid == 0) { counts[0] = total_v; counts[1] = 2048 - total_v; }
}

// ---------------- m97-style bf16 GEMM, indirect A rows, per-expert weights ----------------
template <typename OutT>
__global__ __launch_bounds__(256) void gemm_expert(
    const u16* __restrict__ A, const u16* __restrict__ BtVis, const u16* __restrict__ BtLang,
    OutT* __restrict__ C, const int* __restrict__ lists, const int* __restrict__ counts, int ldc) {
    const int e = blockIdx.z;
    const int cnt = counts[e];
    const int m0 = blockIdx.y * 128;
    if (m0 >= cnt) return;
    const u16* Bt = (e == 0) ? BtVis : BtLang;
    const int* list = lists + e * 2048;
    const int n0 = blockIdx.x * 128;
    const int tid = threadIdx.x, lane = tid & 63, w = tid >> 6;
    const int wm = w >> 1, wn = w & 1;
    const int l16 = lane & 15, quad = lane >> 4;

    __shared__ __align__(16) u16 As[128 * 32];
    __shared__ __align__(16) u16 Bs[128 * 32];

    const int c0 = w * 2, c1 = c0 + 1;
    const int r0 = c0 * 16 + (lane >> 2);
    const int r1 = c1 * 16 + (lane >> 2);
    const int kb = (lane & 3) * 16;   // bytes within 64B row window

    const char* a0  = (const char*)(A + (size_t)list[min(m0 + r0, cnt - 1)] * D_MODEL) + kb;
    const char* a1  = (const char*)(A + (size_t)list[min(m0 + r1, cnt - 1)] * D_MODEL) + kb;
    const char* b0p = (const char*)(Bt + (size_t)(n0 + r0) * D_MODEL) + kb;
    const char* b1p = (const char*)(Bt + (size_t)(n0 + r1) * D_MODEL) + kb;
    u16* asd0 = As + c0 * 512; u16* asd1 = As + c1 * 512;
    u16* bsd0 = Bs + c0 * 512; u16* bsd1 = Bs + c1 * 512;

    f32x4 acc[4][4] = {};

    for (int k0 = 0; k0 < D_MODEL * 2; k0 += 64) {   // k0 in BYTES (32 elems)
        __syncthreads();
        gload_lds16(a0 + k0, asd0);
        gload_lds16(a1 + k0, asd1);
        gload_lds16(b0p + k0, bsd0);
        gload_lds16(b1p + k0, bsd1);
        __syncthreads();
        bf16x8 af[4], bfr[4];
#pragma unroll
        for (int mi = 0; mi < 4; ++mi)
            af[mi] = *(const bf16x8*)&As[(wm * 64 + mi * 16 + l16) * 32 + quad * 8];
#pragma unroll
        for (int ni = 0; ni < 4; ++ni)
            bfr[ni] = *(const bf16x8*)&Bs[(wn * 64 + ni * 16 + l16) * 32 + quad * 8];
#pragma unroll
        for (int mi = 0; mi < 4; ++mi)
#pragma unroll
            for (int ni = 0; ni < 4; ++ni)
                acc[mi][ni] = mfma_bf16(af[mi], bfr[ni], acc[mi][ni]);
    }

#pragma unroll
    for (int mi = 0; mi < 4; ++mi) {
#pragma unroll
        for (int r = 0; r < 4; ++r) {
            int slot = m0 + wm * 64 + mi * 16 + quad * 4 + r;
            if (slot < cnt) {
                int row = list[slot];
                size_t rb = (size_t)row * ldc + n0 + wn * 64 + l16;
#pragma unroll
                for (int ni = 0; ni < 4; ++ni) {
                    float v = acc[mi][ni][r];
                    if constexpr (sizeof(OutT) == 2) C[rb + ni * 16] = (OutT)f2bf(v);
                    else                             C[rb + ni * 16] = v;
                }
            }
        }
    }
}

// ---------------- RoPE in-place on q,k halves of QKV (bf16) ----------------
// position_ids arrives as int32 per harness contract ("integer -> const int*"),
// but hedge with a runtime format probe: if the buffer is int64(arange),
// the int32 view is [0,0,1,0,2,0,...] so i32[1]==0; if int32, i32[1]==1.
__global__ __launch_bounds__(256) void rope_kernel(u16* __restrict__ qkv,
                                                   const int* __restrict__ posi) {
    int idx = blockIdx.x * 256 + threadIdx.x;    // [0, 2048*32*64)
    int t = idx >> 11;
    int rem = idx & 2047;
    int h = rem >> 6;
    int j = rem & 63;
    int l = t & (L_SEQ - 1);
    int is_i32 = posi[1];                          // 1 => int32 layout, 0 => int64 layout
    int pv = is_i32 ? posi[l] : posi[2 * l];       // int64 low word (positions < 2^31)
    float p = (float)pv;
    float inv = expf(-(float)j * 0.14391156831212787f);  // ln(10000)/64
    float ang = p * inv;
    float s, c;
    sincosf(ang, &s, &c);
    size_t base = (size_t)t * NQKV + h * DH + j;
    float x1 = bf2f(qkv[base]), x2 = bf2f(qkv[base + 64]);
    qkv[base]      = f2bf(x1 * c - x2 * s);
    qkv[base + 64] = f2bf(x2 * c + x1 * s);
    size_t kb = base + D_MODEL;
    x1 = bf2f(qkv[kb]); x2 = bf2f(qkv[kb + 64]);
    qkv[kb]      = f2bf(x1 * c - x2 * s);
    qkv[kb + 64] = f2bf(x2 * c + x1 * s);
}

// ---------------- flash attention (causal), MFMA QK^T and PV ----------------
__global__ __launch_bounds__(256) void attn_kernel(const u16* __restrict__ qkv,
                                                   u16* __restrict__ ctx) {
    const int qt = blockIdx.x, h = blockIdx.y, b = blockIdx.z;
    const int tid = threadIdx.x, lane = tid & 63, w = tid >> 6;
    const int quad = lane >> 4, l16 = lane & 15;

    __shared__ __align__(16) u16 Qs[64 * 128];
    __shared__ __align__(16) u16 Ks[32 * 128];
    __shared__ __align__(16) u16 Vt[128 * 32];
    __shared__ __align__(16) u16 Ps[4][16 * 32];

    const size_t qbase = ((size_t)(b * L_SEQ + qt * 64)) * NQKV + h * DH;
    for (int idx = tid; idx < 64 * 16; idx += 256) {
        int r = idx >> 4, c = idx & 15;
        *(u16x8*)&Qs[r * 128 + c * 8] = *(const u16x8*)&qkv[qbase + (size_t)r * NQKV + c * 8];
    }

    float m_i[4], l_i[4];
    f32x4 o[8] = {};
#pragma unroll
    for (int r = 0; r < 4; ++r) { m_i[r] = -1e30f; l_i[r] = 0.f; }
    const float scale = 0.08838834764831845f;  // 1/sqrt(128)
    const int jmax = 2 * qt + 2;

    for (int jt = 0; jt < jmax; ++jt) {
        __syncthreads();
        const size_t kb = ((size_t)(b * L_SEQ + jt * 32)) * NQKV + D_MODEL + h * DH;
        const size_t vb = kb + D_MODEL;
        for (int idx = tid; idx < 32 * 16; idx += 256) {
            int r = idx >> 4, c = idx & 15;
            *(u16x8*)&Ks[r * 128 + c * 8] = *(const u16x8*)&qkv[kb + (size_t)r * NQKV + c * 8];
            u16x8 v = *(const u16x8*)&qkv[vb + (size_t)r * NQKV + c * 8];
#pragma unroll
            for (int jj = 0; jj < 8; ++jj) Vt[(c * 8 + jj) * 32 + r] = v[jj];
        }
        __syncthreads();

        f32x4 s0 = {0.f, 0.f, 0.f, 0.f}, s1 = {0.f, 0.f, 0.f, 0.f};
#pragma unroll
        for (int kc = 0; kc < 4; ++kc) {
            bf16x8 aq  = *(const bf16x8*)&Qs[(w * 16 + l16) * 128 + kc * 32 + quad * 8];
            bf16x8 bk0 = *(const bf16x8*)&Ks[l16 * 128 + kc * 32 + quad * 8];
            bf16x8 bk1 = *(const bf16x8*)&Ks[(16 + l16) * 128 + kc * 32 + quad * 8];
            s0 = mfma_bf16(aq, bk0, s0);
            s1 = mfma_bf16(aq, bk1, s1);
        }

        const int qg = qt * 64 + w * 16 + quad * 4;
        const int kg0 = jt * 32 + l16, kg1 = kg0 + 16;
        float sv0[4], sv1[4], mx[4];
#pragma unroll
        for (int r = 0; r < 4; ++r) {
            sv0[r] = (kg0 <= qg + r) ? s0[r] * scale : -1e30f;
            sv1[r] = (kg1 <= qg + r) ? s1[r] * scale : -1e30f;
            mx[r] = fmaxf(sv0[r], sv1[r]);
        }
#pragma unroll
        for (int d = 1; d < 16; d <<= 1)
#pragma unroll
            for (int r = 0; r < 4; ++r) mx[r] = fmaxf(mx[r], __shfl_xor(mx[r], d));
        float alpha[4], p0[4], p1[4], rs[4];
#pragma unroll
        for (int r = 0; r < 4; ++r) {
            float mn = fmaxf(m_i[r], mx[r]);
            alpha[r] = __expf(m_i[r] - mn);
            m_i[r] = mn;
            p0[r] = __expf(sv0[r] - mn);
            p1[r] = __expf(sv1[r] - mn);
            rs[r] = p0[r] + p1[r];
        }
#pragma unroll
        for (int d = 1; d < 16; d <<= 1)
#pragma unroll
            for (int r = 0; r < 4; ++r) rs[r] += __shfl_xor(rs[r], d);
#pragma unroll
        for (int r = 0; r < 4; ++r) {
            l_i[r] = l_i[r] * alpha[r] + rs[r];
            Ps[w][(quad * 4 + r) * 32 + l16]      = f2bf(p0[r]);
            Ps[w][(quad * 4 + r) * 32 + 16 + l16] = f2bf(p1[r]);
        }
#pragma unroll
        for (int n = 0; n < 8; ++n)
#pragma unroll
            for (int r = 0; r < 4; ++r) o[n][r] *= alpha[r];
        __syncthreads();  // P C-layout -> A-layout LDS round-trip visibility
        bf16x8 ap = *(const bf16x8*)&Ps[w][l16 * 32 + quad * 8];
#pragma unroll
        for (int n = 0; n < 8; ++n) {
            bf16x8 bv = *(const bf16x8*)&Vt[(n * 16 + l16) * 32 + quad * 8];
            o[n] = mfma_bf16(ap, bv, o[n]);
        }
    }

    const int tglob = b * L_SEQ + qt * 64 + w * 16 + quad * 4;
#pragma unroll
    for (int r = 0; r < 4; ++r) {
        float invl = 1.f / l_i[r];
#pragma unroll
        for (int n = 0; n < 8; ++n)
            ctx[(size_t)(tglob + r) * D_MODEL + h * DH + n * 16 + l16] = f2bf(o[n][r] * invl);
    }
}

extern "C" void kernel_launch(void* const* d_in, const int* in_sizes, int n_in,
                              void* d_out, int out_size, void* d_ws, size_t ws_size,
                              hipStream_t stream) {
    const float* hidden = (const float*)d_in[0];
    const int* tt = (const int*)d_in[1];
    const int* pos = (const int*)d_in[2];
    const float* wqv = (const float*)d_in[3];
    const float* wql = (const float*)d_in[4];
    const float* wdv = (const float*)d_in[5];
    const float* wdl = (const float*)d_in[6];
    float* out = (float*)d_out;

    char* ws = (char*)d_ws;
    size_t off = 0;
    auto alloc = [&](size_t bytes) {
        char* p = ws + off;
        off += (bytes + 255) & ~(size_t)255;
        return p;
    };
    u16* WqvT = (u16*)alloc((size_t)NQKV * D_MODEL * 2);
    u16* WqlT = (u16*)alloc((size_t)NQKV * D_MODEL * 2);
    u16* WdvT = (u16*)alloc((size_t)D_MODEL * D_MODEL * 2);
    u16* WdlT = (u16*)alloc((size_t)D_MODEL * D_MODEL * 2);
    u16* Abf  = (u16*)alloc((size_t)BL * D_MODEL * 2);
    u16* QKV  = (u16*)alloc((size_t)BL * NQKV * 2);
    u16* CTX  = (u16*)alloc((size_t)BL * D_MODEL * 2);
    int* lists  = (int*)alloc(4096 * sizeof(int));
    int* counts = (int*)alloc(256);

    convert_f32_bf16<<<BL * D_MODEL / 4 / 256, 256, 0, stream>>>(hidden, Abf, BL * D_MODEL / 4);
    transpose_convert<<<dim3(NQKV / 32, D_MODEL / 32), dim3(32, 8), 0, stream>>>(wqv, WqvT, D_MODEL, NQKV);
    transpose_convert<<<dim3(NQKV / 32, D_MODEL / 32), dim3(32, 8), 0, stream>>>(wql, WqlT, D_MODEL, NQKV);
    transpose_convert<<<dim3(D_MODEL / 32, D_MODEL / 32), dim3(32, 8), 0, stream>>>(wdv, WdvT, D_MODEL, D_MODEL);
    transpose_convert<<<dim3(D_MODEL / 32, D_MODEL / 32), dim3(32, 8), 0, stream>>>(wdl, WdlT, D_MODEL, D_MODEL);
    mask_scan<<<1, 256, 0, stream>>>(tt, lists, counts);
    gemm_expert<u16><<<dim3(NQKV / 128, 16, 2), 256, 0, stream>>>(Abf, WqvT, WqlT, QKV, lists, counts, NQKV);
    rope_kernel<<<BL * NH * 64 / 256, 256, 0, stream>>>(QKV, pos);
    attn_kernel<<<dim3(16, NH, 2), 256, 0, stream>>>(QKV, CTX);
    gemm_expert<float><<<dim3(D_MODEL / 128, 16, 2), 256, 0, stream>>>(CTX, WdvT, WdlT, out, lists, counts, D_MODEL);
}